// Round 5
// baseline (137.187 us; speedup 1.0000x reference)
//
#include <hip/hip_runtime.h>

// Problem constants (GraphConvolution_71923522339430)
#define D_IN  128
#define D_OUT 64

// Native clang vector type for nontemporal builtins (HIP_vector_type float4
// is rejected by __builtin_nontemporal_*; ext_vector_type is accepted and
// layout-identical).
typedef float f32x4 __attribute__((ext_vector_type(4)));

// h is stored in WORKSPACE as bf16: halves the aggregate gather volume
// (205 -> 102 MB from L2/LLC) and gemm's h-write traffic.
// Accuracy budget: bf16 rounding of h adds ~2^-8 relative per term, deg~16,
// expected absmax ~0.05-0.1 vs 0.3375 threshold (round-3 slack: 0.031).

// f32x4 -> packed bf16x4 (round-to-nearest-even), little-endian in uint2.
__device__ inline uint2 pack_bf16x4(float4 f) {
    unsigned ux = __float_as_uint(f.x), uy = __float_as_uint(f.y);
    unsigned uz = __float_as_uint(f.z), uw = __float_as_uint(f.w);
    unsigned rx = (ux + 0x7fffu + ((ux >> 16) & 1u)) >> 16;
    unsigned ry = (uy + 0x7fffu + ((uy >> 16) & 1u)) >> 16;
    unsigned rz = (uz + 0x7fffu + ((uz >> 16) & 1u)) >> 16;
    unsigned rw = (uw + 0x7fffu + ((uw >> 16) & 1u)) >> 16;
    uint2 r;
    r.x = (rx & 0xffffu) | (ry << 16);
    r.y = (rz & 0xffffu) | (rw << 16);
    return r;
}

// packed bf16x4 (uint2) -> f32x4
__device__ inline float4 unpack_bf16x4(uint2 u) {
    float4 f;
    f.x = __uint_as_float(u.x << 16);
    f.y = __uint_as_float(u.x & 0xffff0000u);
    f.z = __uint_as_float(u.y << 16);
    f.w = __uint_as_float(u.y & 0xffff0000u);
    return f;
}

// ---------------------------------------------------------------------------
// Kernel 1: h = x @ W   ([N,128] @ [128,64] f32 compute -> bf16 store)
// Block = 256 threads, 64 nodes per block. 4x4 register tile per thread.
// All LDS reads ds_read_b128; Xs stride 132 -> conflict-free broadcast.
// launch_bounds(256,4) caps VGPR at 128 (round-1 spill insurance).
// ---------------------------------------------------------------------------
__global__ __launch_bounds__(256, 4) void gemm_h_kernel(
    const float* __restrict__ x, const float* __restrict__ w,
    unsigned* __restrict__ h2, int n_nodes)   // h2: bf16 pairs, 32 uints/row
{
    __shared__ float Xs[64 * 132];   // 33792 B
    __shared__ float Ws[128 * 64];   // 32768 B

    const int t   = threadIdx.x;
    const int tx  = t & 15;          // dim group
    const int ty  = t >> 4;          // node group
    const int node0 = blockIdx.x * 64;

    // Stage W: 2048 float4, 8 per thread.
    #pragma unroll
    for (int j = 0; j < 8; ++j) {
        int idx = j * 256 + t;
        int k   = idx >> 4;
        int c   = idx & 15;
        float4 v = *(const float4*)&w[k * D_OUT + c * 4];
        *(float4*)&Ws[k * 64 + c * 4] = v;
    }
    // Stage X tile: 64 rows x 128 floats (streaming input -> nontemporal).
    #pragma unroll
    for (int j = 0; j < 8; ++j) {
        int idx = j * 256 + t;
        int r   = idx >> 5;
        int c   = idx & 31;
        int gn  = node0 + r;
        f32x4 v = (f32x4){0.f, 0.f, 0.f, 0.f};
        if (gn < n_nodes)
            v = __builtin_nontemporal_load((const f32x4*)&x[(size_t)gn * D_IN + c * 4]);
        *(f32x4*)&Xs[r * 132 + c * 4] = v;
    }
    __syncthreads();

    float4 acc[4];
    #pragma unroll
    for (int i = 0; i < 4; ++i) acc[i] = make_float4(0.f, 0.f, 0.f, 0.f);

    const int d0 = tx * 4;
    const int n0 = ty * 4;

    #pragma unroll 2
    for (int k = 0; k < D_IN; k += 4) {
        float4 xa[4], wb[4];
        #pragma unroll
        for (int i = 0; i < 4; ++i)
            xa[i] = *(const float4*)&Xs[(n0 + i) * 132 + k];
        #pragma unroll
        for (int r = 0; r < 4; ++r)
            wb[r] = *(const float4*)&Ws[(k + r) * 64 + d0];
        #pragma unroll
        for (int i = 0; i < 4; ++i) {
            acc[i].x = fmaf(xa[i].x, wb[0].x, acc[i].x);
            acc[i].y = fmaf(xa[i].x, wb[0].y, acc[i].y);
            acc[i].z = fmaf(xa[i].x, wb[0].z, acc[i].z);
            acc[i].w = fmaf(xa[i].x, wb[0].w, acc[i].w);
            acc[i].x = fmaf(xa[i].y, wb[1].x, acc[i].x);
            acc[i].y = fmaf(xa[i].y, wb[1].y, acc[i].y);
            acc[i].z = fmaf(xa[i].y, wb[1].z, acc[i].z);
            acc[i].w = fmaf(xa[i].y, wb[1].w, acc[i].w);
            acc[i].x = fmaf(xa[i].z, wb[2].x, acc[i].x);
            acc[i].y = fmaf(xa[i].z, wb[2].y, acc[i].y);
            acc[i].z = fmaf(xa[i].z, wb[2].z, acc[i].z);
            acc[i].w = fmaf(xa[i].z, wb[2].w, acc[i].w);
            acc[i].x = fmaf(xa[i].w, wb[3].x, acc[i].x);
            acc[i].y = fmaf(xa[i].w, wb[3].y, acc[i].y);
            acc[i].z = fmaf(xa[i].w, wb[3].z, acc[i].z);
            acc[i].w = fmaf(xa[i].w, wb[3].w, acc[i].w);
        }
    }

    // Epilogue: pack each node-row chunk (4 dims) to bf16x4 = 8B store.
    // Row = 32 uints; 16 dim-lanes x 8B = 128B contiguous per node row.
    #pragma unroll
    for (int i = 0; i < 4; ++i) {
        int gn = node0 + n0 + i;
        if (gn < n_nodes) {
            uint2 p = pack_bf16x4(acc[i]);
            *(uint2*)&h2[(size_t)gn * 32 + tx * 2] = p;   // keep cached: re-read by aggregate
        }
    }
}

// ---------------------------------------------------------------------------
// Kernel 2: build CSR row_ptr from sorted edge_dst.
// ---------------------------------------------------------------------------
__global__ __launch_bounds__(256) void build_row_ptr_kernel(
    const int* __restrict__ dst, int* __restrict__ row_ptr, int n_edges, int n_nodes)
{
    int e = blockIdx.x * blockDim.x + threadIdx.x;
    if (e >= n_edges) return;
    int d1 = dst[e];
    int d0 = (e == 0) ? -1 : dst[e - 1];
    for (int j = d0 + 1; j <= d1; ++j) row_ptr[j] = e;
    if (e == n_edges - 1) {
        for (int j = d1 + 1; j <= n_nodes; ++j) row_ptr[j] = n_edges;
    }
}

// ---------------------------------------------------------------------------
// Kernel 3: out[i][:] = bias + sum_e vals[e] * h[src[e]][:]   (h in bf16)
// One wave per node: lane = (sub = lane>>4) edge slot x (d4 = lane&15) chunk.
// Each lane loads 4 bf16 dims (8B, uint2); 16 lanes x 8B = one 128B bf16 row
// per edge slot; 4 slots/instr, 2x unroll -> 8 gathers in flight.
// Cross-sub reduce via shfl_xor(16|32); sub==0 lanes store f32x4 + bias,
// nontemporal (out never re-read -> don't evict h from L2).
// ---------------------------------------------------------------------------
__global__ __launch_bounds__(256) void aggregate_kernel(
    const uint2* __restrict__ h2, const int* __restrict__ src,
    const float* __restrict__ vals, const int* __restrict__ row_ptr,
    const float* __restrict__ bias, float* __restrict__ out, int n_nodes)
{
    int wave = (blockIdx.x * blockDim.x + threadIdx.x) >> 6;
    int lane = threadIdx.x & 63;
    if (wave >= n_nodes) return;
    int sub = lane >> 4;      // edge slot 0..3
    int d4  = lane & 15;      // bf16x4 chunk of the 64-dim row

    int b = row_ptr[wave];
    int e = row_ptr[wave + 1];

    float4 acc = make_float4(0.f, 0.f, 0.f, 0.f);
    int k = b + sub;
    for (; k + 4 < e; k += 8) {
        int   s0 = __builtin_nontemporal_load(&src[k]);
        float v0 = __builtin_nontemporal_load(&vals[k]);
        int   s1 = __builtin_nontemporal_load(&src[k + 4]);
        float v1 = __builtin_nontemporal_load(&vals[k + 4]);
        uint2 r0 = h2[(size_t)s0 * 16 + d4];
        uint2 r1 = h2[(size_t)s1 * 16 + d4];
        float4 h0 = unpack_bf16x4(r0);
        float4 h1 = unpack_bf16x4(r1);
        acc.x = fmaf(v0, h0.x, acc.x);
        acc.y = fmaf(v0, h0.y, acc.y);
        acc.z = fmaf(v0, h0.z, acc.z);
        acc.w = fmaf(v0, h0.w, acc.w);
        acc.x = fmaf(v1, h1.x, acc.x);
        acc.y = fmaf(v1, h1.y, acc.y);
        acc.z = fmaf(v1, h1.z, acc.z);
        acc.w = fmaf(v1, h1.w, acc.w);
    }
    if (k < e) {
        int   s0 = src[k];
        float v0 = vals[k];
        float4 h0 = unpack_bf16x4(h2[(size_t)s0 * 16 + d4]);
        acc.x = fmaf(v0, h0.x, acc.x);
        acc.y = fmaf(v0, h0.y, acc.y);
        acc.z = fmaf(v0, h0.z, acc.z);
        acc.w = fmaf(v0, h0.w, acc.w);
    }

    // Sum across the 4 edge slots (lanes differing in bits 4,5).
    #pragma unroll
    for (int off = 16; off < 64; off <<= 1) {
        acc.x += __shfl_xor(acc.x, off, 64);
        acc.y += __shfl_xor(acc.y, off, 64);
        acc.z += __shfl_xor(acc.z, off, 64);
        acc.w += __shfl_xor(acc.w, off, 64);
    }

    if (sub == 0) {
        float4 bb = *(const float4*)&bias[d4 * 4];
        f32x4 o;
        o.x = acc.x + bb.x;
        o.y = acc.y + bb.y;
        o.z = acc.z + bb.z;
        o.w = acc.w + bb.w;
        __builtin_nontemporal_store(o, (f32x4*)&out[(size_t)wave * D_OUT + d4 * 4]);
    }
}

// ---------------------------------------------------------------------------
extern "C" void kernel_launch(void* const* d_in, const int* in_sizes, int n_in,
                              void* d_out, int out_size, void* d_ws, size_t ws_size,
                              hipStream_t stream)
{
    const float* x         = (const float*)d_in[0];
    const int*   edge_src  = (const int*)  d_in[1];
    const int*   edge_dst  = (const int*)  d_in[2];
    const float* edge_vals = (const float*)d_in[3];
    const float* weight    = (const float*)d_in[4];
    const float* bias      = (const float*)d_in[5];
    float*       out       = (float*)d_out;

    const int n_nodes = in_sizes[0] / D_IN;   // 50000
    const int n_edges = in_sizes[1];          // 800000

    // Workspace layout: h_bf16 [n_nodes*64 bf16 = n_nodes*32 uint] | row_ptr
    unsigned* h2      = (unsigned*)d_ws;
    int*      row_ptr = (int*)((char*)d_ws + (size_t)n_nodes * 32 * sizeof(unsigned));

    // 1) h = x @ W  (bf16 store)
    {
        dim3 grid((n_nodes + 63) / 64), block(256);
        hipLaunchKernelGGL(gemm_h_kernel, grid, block, 0, stream, x, weight, h2, n_nodes);
    }
    // 2) row_ptr from sorted edge_dst
    {
        dim3 grid((n_edges + 255) / 256), block(256);
        hipLaunchKernelGGL(build_row_ptr_kernel, grid, block, 0, stream,
                           edge_dst, row_ptr, n_edges, n_nodes);
    }
    // 3) aggregate + bias
    {
        dim3 grid((n_nodes + 3) / 4), block(256);   // 4 waves/block, 1 wave/node
        hipLaunchKernelGGL(aggregate_kernel, grid, block, 0, stream,
                           (const uint2*)h2, edge_src, edge_vals, row_ptr, bias, out, n_nodes);
    }
}

// Round 6
// 133.912 us; speedup vs baseline: 1.0245x; 1.0245x over previous
//
#include <hip/hip_runtime.h>

// Problem constants (GraphConvolution_71923522339430)
#define D_IN  128
#define D_OUT 64
#define GEMM_NODES_PER_BLOCK 64

// Native clang vector type for nontemporal builtins (HIP_vector_type float4
// is rejected by __builtin_nontemporal_*; ext_vector_type is accepted and
// layout-identical).
typedef float f32x4 __attribute__((ext_vector_type(4)));

// h lives in WORKSPACE as bf16: halves gather volume vs f32 (absmax 0.0625
// vs threshold 0.3375 — verified round 5).

// f32x4 -> packed bf16x4 (round-to-nearest-even), little-endian in uint2.
__device__ inline uint2 pack_bf16x4(float4 f) {
    unsigned ux = __float_as_uint(f.x), uy = __float_as_uint(f.y);
    unsigned uz = __float_as_uint(f.z), uw = __float_as_uint(f.w);
    unsigned rx = (ux + 0x7fffu + ((ux >> 16) & 1u)) >> 16;
    unsigned ry = (uy + 0x7fffu + ((uy >> 16) & 1u)) >> 16;
    unsigned rz = (uz + 0x7fffu + ((uz >> 16) & 1u)) >> 16;
    unsigned rw = (uw + 0x7fffu + ((uw >> 16) & 1u)) >> 16;
    uint2 r;
    r.x = (rx & 0xffffu) | (ry << 16);
    r.y = (rz & 0xffffu) | (rw << 16);
    return r;
}

// packed bf16x4 (uint2) -> f32x4
__device__ inline float4 unpack_bf16x4(uint2 u) {
    float4 f;
    f.x = __uint_as_float(u.x << 16);
    f.y = __uint_as_float(u.x & 0xffff0000u);
    f.z = __uint_as_float(u.y << 16);
    f.w = __uint_as_float(u.y & 0xffff0000u);
    return f;
}

// ---------------------------------------------------------------------------
// Fused kernel 1: blocks [0, gemm_blocks) compute h = x @ W (f32 compute,
// bf16 store); blocks [gemm_blocks, gemm_blocks + rp_blocks) build the CSR
// row_ptr from sorted edge_dst. The two jobs touch disjoint data (x,w,h2 vs
// edge_dst,row_ptr), so fusing removes one launch and runs row_ptr for free
// in gemm's shadow (round-6 change; rounds 2-5 serialized them).
// GEMM: 64 nodes/block, 4x4 register tile/thread, all-b128 LDS reads,
// Xs stride 132 (conflict-free 4-row broadcast, 16B-aligned).
// launch_bounds(256,4) caps VGPR at 128 (round-1 spill insurance).
// ---------------------------------------------------------------------------
__global__ __launch_bounds__(256, 4) void gemm_rowptr_kernel(
    const float* __restrict__ x, const float* __restrict__ w,
    unsigned* __restrict__ h2, int n_nodes,
    const int* __restrict__ dst, int* __restrict__ row_ptr, int n_edges,
    int gemm_blocks)
{
    const int t = threadIdx.x;

    if ((int)blockIdx.x >= gemm_blocks) {
        // ---- row_ptr part: 8 edges per thread, coalesced stride-256 ----
        int base = ((int)blockIdx.x - gemm_blocks) * 2048;
        #pragma unroll
        for (int j = 0; j < 8; ++j) {
            int e = base + j * 256 + t;
            if (e >= n_edges) break;
            int d1 = dst[e];
            int d0 = (e == 0) ? -1 : dst[e - 1];
            for (int q = d0 + 1; q <= d1; ++q) row_ptr[q] = e;
            if (e == n_edges - 1) {
                for (int q = d1 + 1; q <= n_nodes; ++q) row_ptr[q] = n_edges;
            }
        }
        return;
    }

    // ---- GEMM part ----
    __shared__ float Xs[64 * 132];   // 33792 B
    __shared__ float Ws[128 * 64];   // 32768 B

    const int tx  = t & 15;          // dim group
    const int ty  = t >> 4;          // node group
    const int node0 = blockIdx.x * GEMM_NODES_PER_BLOCK;

    // Stage W: 2048 float4, 8 per thread.
    #pragma unroll
    for (int j = 0; j < 8; ++j) {
        int idx = j * 256 + t;
        int k   = idx >> 4;
        int c   = idx & 15;
        float4 v = *(const float4*)&w[k * D_OUT + c * 4];
        *(float4*)&Ws[k * 64 + c * 4] = v;
    }
    // Stage X tile: 64 rows x 128 floats (streamed once -> nontemporal).
    #pragma unroll
    for (int j = 0; j < 8; ++j) {
        int idx = j * 256 + t;
        int r   = idx >> 5;
        int c   = idx & 31;
        int gn  = node0 + r;
        f32x4 v = (f32x4){0.f, 0.f, 0.f, 0.f};
        if (gn < n_nodes)
            v = __builtin_nontemporal_load((const f32x4*)&x[(size_t)gn * D_IN + c * 4]);
        *(f32x4*)&Xs[r * 132 + c * 4] = v;
    }
    __syncthreads();

    float4 acc[4];
    #pragma unroll
    for (int i = 0; i < 4; ++i) acc[i] = make_float4(0.f, 0.f, 0.f, 0.f);

    const int d0 = tx * 4;
    const int n0 = ty * 4;

    #pragma unroll 2
    for (int k = 0; k < D_IN; k += 4) {
        float4 xa[4], wb[4];
        #pragma unroll
        for (int i = 0; i < 4; ++i)
            xa[i] = *(const float4*)&Xs[(n0 + i) * 132 + k];
        #pragma unroll
        for (int r = 0; r < 4; ++r)
            wb[r] = *(const float4*)&Ws[(k + r) * 64 + d0];
        #pragma unroll
        for (int i = 0; i < 4; ++i) {
            acc[i].x = fmaf(xa[i].x, wb[0].x, acc[i].x);
            acc[i].y = fmaf(xa[i].x, wb[0].y, acc[i].y);
            acc[i].z = fmaf(xa[i].x, wb[0].z, acc[i].z);
            acc[i].w = fmaf(xa[i].x, wb[0].w, acc[i].w);
            acc[i].x = fmaf(xa[i].y, wb[1].x, acc[i].x);
            acc[i].y = fmaf(xa[i].y, wb[1].y, acc[i].y);
            acc[i].z = fmaf(xa[i].y, wb[1].z, acc[i].z);
            acc[i].w = fmaf(xa[i].y, wb[1].w, acc[i].w);
            acc[i].x = fmaf(xa[i].z, wb[2].x, acc[i].x);
            acc[i].y = fmaf(xa[i].z, wb[2].y, acc[i].y);
            acc[i].z = fmaf(xa[i].z, wb[2].z, acc[i].z);
            acc[i].w = fmaf(xa[i].z, wb[2].w, acc[i].w);
            acc[i].x = fmaf(xa[i].w, wb[3].x, acc[i].x);
            acc[i].y = fmaf(xa[i].w, wb[3].y, acc[i].y);
            acc[i].z = fmaf(xa[i].w, wb[3].z, acc[i].z);
            acc[i].w = fmaf(xa[i].w, wb[3].w, acc[i].w);
        }
    }

    // Epilogue: pack to bf16x4, 8B store; row = 32 uints (128B), coalesced
    // across the 16 dim-lanes. Kept cacheable: re-read by aggregate.
    #pragma unroll
    for (int i = 0; i < 4; ++i) {
        int gn = node0 + n0 + i;
        if (gn < n_nodes) {
            uint2 p = pack_bf16x4(acc[i]);
            *(uint2*)&h2[(size_t)gn * 32 + tx * 2] = p;
        }
    }
}

// ---------------------------------------------------------------------------
// Kernel 2: out[i][:] = bias + sum_e vals[e] * h[src[e]][:]   (h in bf16)
// One wave per node: lane = (sub = lane>>4) edge slot x (d4 = lane&15) chunk.
// Each lane loads 4 bf16 dims (8B uint2); 16 lanes = one 128B bf16 row per
// edge slot; 4 slots/instr, 2x unroll -> 8 gathers in flight.
// Cross-sub reduce via shfl_xor(16|32); sub==0 lanes store f32x4 + bias,
// nontemporal (out never re-read -> don't evict h from L2).
// ---------------------------------------------------------------------------
__global__ __launch_bounds__(256) void aggregate_kernel(
    const uint2* __restrict__ h2, const int* __restrict__ src,
    const float* __restrict__ vals, const int* __restrict__ row_ptr,
    const float* __restrict__ bias, float* __restrict__ out, int n_nodes)
{
    int wave = (blockIdx.x * blockDim.x + threadIdx.x) >> 6;
    int lane = threadIdx.x & 63;
    if (wave >= n_nodes) return;
    int sub = lane >> 4;      // edge slot 0..3
    int d4  = lane & 15;      // bf16x4 chunk of the 64-dim row

    int b = row_ptr[wave];
    int e = row_ptr[wave + 1];

    float4 acc = make_float4(0.f, 0.f, 0.f, 0.f);
    int k = b + sub;
    for (; k + 4 < e; k += 8) {
        int   s0 = __builtin_nontemporal_load(&src[k]);
        float v0 = __builtin_nontemporal_load(&vals[k]);
        int   s1 = __builtin_nontemporal_load(&src[k + 4]);
        float v1 = __builtin_nontemporal_load(&vals[k + 4]);
        uint2 r0 = h2[(size_t)s0 * 16 + d4];
        uint2 r1 = h2[(size_t)s1 * 16 + d4];
        float4 h0 = unpack_bf16x4(r0);
        float4 h1 = unpack_bf16x4(r1);
        acc.x = fmaf(v0, h0.x, acc.x);
        acc.y = fmaf(v0, h0.y, acc.y);
        acc.z = fmaf(v0, h0.z, acc.z);
        acc.w = fmaf(v0, h0.w, acc.w);
        acc.x = fmaf(v1, h1.x, acc.x);
        acc.y = fmaf(v1, h1.y, acc.y);
        acc.z = fmaf(v1, h1.z, acc.z);
        acc.w = fmaf(v1, h1.w, acc.w);
    }
    if (k < e) {
        int   s0 = src[k];
        float v0 = vals[k];
        float4 h0 = unpack_bf16x4(h2[(size_t)s0 * 16 + d4]);
        acc.x = fmaf(v0, h0.x, acc.x);
        acc.y = fmaf(v0, h0.y, acc.y);
        acc.z = fmaf(v0, h0.z, acc.z);
        acc.w = fmaf(v0, h0.w, acc.w);
    }

    // Sum across the 4 edge slots (lanes differing in bits 4,5).
    #pragma unroll
    for (int off = 16; off < 64; off <<= 1) {
        acc.x += __shfl_xor(acc.x, off, 64);
        acc.y += __shfl_xor(acc.y, off, 64);
        acc.z += __shfl_xor(acc.z, off, 64);
        acc.w += __shfl_xor(acc.w, off, 64);
    }

    if (sub == 0) {
        float4 bb = *(const float4*)&bias[d4 * 4];
        f32x4 o;
        o.x = acc.x + bb.x;
        o.y = acc.y + bb.y;
        o.z = acc.z + bb.z;
        o.w = acc.w + bb.w;
        __builtin_nontemporal_store(o, (f32x4*)&out[(size_t)wave * D_OUT + d4 * 4]);
    }
}

// ---------------------------------------------------------------------------
extern "C" void kernel_launch(void* const* d_in, const int* in_sizes, int n_in,
                              void* d_out, int out_size, void* d_ws, size_t ws_size,
                              hipStream_t stream)
{
    const float* x         = (const float*)d_in[0];
    const int*   edge_src  = (const int*)  d_in[1];
    const int*   edge_dst  = (const int*)  d_in[2];
    const float* edge_vals = (const float*)d_in[3];
    const float* weight    = (const float*)d_in[4];
    const float* bias      = (const float*)d_in[5];
    float*       out       = (float*)d_out;

    const int n_nodes = in_sizes[0] / D_IN;   // 50000
    const int n_edges = in_sizes[1];          // 800000

    // Workspace layout: h_bf16 [n_nodes*64 bf16 = n_nodes*32 uint] | row_ptr
    unsigned* h2      = (unsigned*)d_ws;
    int*      row_ptr = (int*)((char*)d_ws + (size_t)n_nodes * 32 * sizeof(unsigned));

    // 1) fused: h = x @ W (bf16 store)  ||  row_ptr from sorted edge_dst
    {
        int gemm_blocks = (n_nodes + GEMM_NODES_PER_BLOCK - 1) / GEMM_NODES_PER_BLOCK; // 782
        int rp_blocks   = (n_edges + 2047) / 2048;                                      // 391
        dim3 grid(gemm_blocks + rp_blocks), block(256);
        hipLaunchKernelGGL(gemm_rowptr_kernel, grid, block, 0, stream,
                           x, weight, h2, n_nodes,
                           edge_dst, row_ptr, n_edges, gemm_blocks);
    }
    // 2) aggregate + bias
    {
        dim3 grid((n_nodes + 3) / 4), block(256);   // 4 waves/block, 1 wave/node
        hipLaunchKernelGGL(aggregate_kernel, grid, block, 0, stream,
                           (const uint2*)h2, edge_src, edge_vals, row_ptr, bias, out, n_nodes);
    }
}